// Round 6
// baseline (3370.007 us; speedup 1.0000x reference)
//
#include <hip/hip_runtime.h>
#include <hip/hip_bf16.h>
#include <stdint.h>

typedef _Float16 f16;
typedef _Float16 f16x8 __attribute__((ext_vector_type(8)));
typedef float f32x16 __attribute__((ext_vector_type(16)));
typedef float f32x4 __attribute__((ext_vector_type(4)));
typedef uint32_t u32x4 __attribute__((ext_vector_type(4)));
typedef uint32_t u32x2 __attribute__((ext_vector_type(2)));

#define MFMA(A, B, C) __builtin_amdgcn_mfma_f32_32x32x16_f16((A), (B), (C), 0, 0, 0)

// ---------------------------------------------------------------------------
// Kernel 1: x NCHW f32 [32,256,64,64] -> xt f16, MFMA-native layout:
//   byte = (b*64+h)*32768 + c32*4096 + g*1024 + (w&1)*512 + (w>>1)*16 + e*2
//   (c = c32*32 + g*8 + e). A-fragment loads are contiguous 512B runs.
// (unchanged from round 5 — correctness-proven)
// ---------------------------------------------------------------------------
__global__ __launch_bounds__(256) void nchw_to_nhwc_f16(
    const float* __restrict__ x, f16* __restrict__ xt) {
  __shared__ __align__(16) uint32_t tile[64 * 128];  // 32768 B
  const int bh = blockIdx.x;  // b*64 + h
  const int t = threadIdx.x;
  const float* src = x + (size_t)(bh >> 6) * (256 * 4096) + (bh & 63) * 64;

  const int w4 = t & 15;            // float4 index along w
  const int cq = t >> 4;            // c-quad 0..15
  const int xorv = 4 * (w4 & 7);    // = 4*((w>>2)&7) since w = w4*4+jw
#pragma unroll
  for (int it = 0; it < 4; ++it) {
    const int c0 = it * 64 + cq * 4;
    float4 v0 = *(const float4*)(src + (size_t)(c0 + 0) * 4096 + w4 * 4);
    float4 v1 = *(const float4*)(src + (size_t)(c0 + 1) * 4096 + w4 * 4);
    float4 v2 = *(const float4*)(src + (size_t)(c0 + 2) * 4096 + w4 * 4);
    float4 v3 = *(const float4*)(src + (size_t)(c0 + 3) * 4096 + w4 * 4);
    const float* p0 = (const float*)&v0;
    const float* p1 = (const float*)&v1;
    const float* p2 = (const float*)&v2;
    const float* p3 = (const float*)&v3;
    const int u = it * 32 + cq * 2;  // even word index (c-pair)
#pragma unroll
    for (int jw = 0; jw < 4; ++jw) {
      f16 h0 = (f16)p0[jw], h1 = (f16)p1[jw], h2 = (f16)p2[jw], h3 = (f16)p3[jw];
      uint32_t lo = (uint32_t)__builtin_bit_cast(uint16_t, h0) |
                    ((uint32_t)__builtin_bit_cast(uint16_t, h1) << 16);
      uint32_t hi = (uint32_t)__builtin_bit_cast(uint16_t, h2) |
                    ((uint32_t)__builtin_bit_cast(uint16_t, h3) << 16);
      u32x2 pk = {lo, hi};
      const int w = w4 * 4 + jw;
      *(u32x2*)&tile[w * 128 + (u ^ xorv)] = pk;
    }
  }
  __syncthreads();
  f16* dstb = xt + (size_t)bh * 16384;
#pragma unroll
  for (int it = 0; it < 8; ++it) {
    const int n = it * 256 + t;       // local 16B-unit index, 0..2047
    const int w2 = n & 31;
    const int par = (n >> 5) & 1;
    const int g8 = n >> 6;            // c-octet 0..31
    const int w = par + 2 * w2;
    const u32x4 v = *(const u32x4*)&tile[w * 128 + ((g8 * 4) ^ (4 * ((w >> 2) & 7)))];
    *(u32x4*)(dstb + n * 8) = v;
  }
}

// ---------------------------------------------------------------------------
// Kernel 2: W [32co][256ci][9][9] f32 -> wt f16:
//   byte = kk*16384 + cic*2048 + sg*512 + co*16 + e*2, ci = cic*32+s*16+hh*8+e
// (unchanged from round 5 — correctness-proven)
// ---------------------------------------------------------------------------
__global__ __launch_bounds__(256) void pack_w(const float* __restrict__ W,
                                              f16* __restrict__ wt) {
  __shared__ float lds[10368];  // [128 ci][81 kk]
  const int t = threadIdx.x;
  const int co = blockIdx.x >> 1;
  const int cih = blockIdx.x & 1;
  const float* src = W + (size_t)(co * 256 + cih * 128) * 81;
  for (int i = t; i < 10368; i += 256) lds[i] = src[i];
  __syncthreads();
  for (int j = t; j < 1296; j += 256) {
    const int kk = j >> 4;
    const int t16 = j & 15;
    const int cicl = t16 >> 2;       // cic within half, 0..3
    const int sg = t16 & 3;          // s*2 + hh
    const int cin = ((sg >> 1) & 1) * 16 + (sg & 1) * 8;  // ci offset in 32
    f16 tmp[8];
#pragma unroll
    for (int e = 0; e < 8; ++e)
      tmp[e] = (f16)lds[(cicl * 32 + cin + e) * 81 + kk];
    const int cic = cih * 4 + cicl;
    *(f16x8*)&wt[(size_t)(((kk * 8 + cic) * 4 + sg) * 32 + co) * 8] = *(f16x8*)tmp;
  }
}

// ---------------------------------------------------------------------------
// Kernel 3: direct conv, mfma_f32_32x32x16_f16, 2D register-blocked:
// wave tile = 2 images x 2 oh rows x 32 co x 32 ci(cic).
// 1792 blocks x 1 wave (64 thr): blk -> cic = blk&7 (XCD-affine B locality),
// (ip, ohp) = (blk>>3)/14, %14. Per step (j,s,kw): 2 A-loads (per image,
// shared by both oh tiles) + up to 2 B-loads (per oh tile, SHARED across
// images) -> 4 MFMA: 1.0 loads/MFMA (r5 was 1.5) and B traffic halved.
// Flat 198-step fully-unrolled pipeline: A depth-3, B depth-6 slots;
// compiler-tracked waits. NO LDS, NO barriers, NO reduction: writes 8
// cic-partials; epilogue sums.
// ---------------------------------------------------------------------------
__global__ __launch_bounds__(64) void conv_direct(
    const f16* __restrict__ xt, const f16* __restrict__ wt,
    float* __restrict__ convp) {
  const int lane = threadIdx.x & 63;
  const int m = lane & 31;
  const int hh = lane >> 5;

  const int blk = blockIdx.x;
  const int cic = blk & 7;            // XCD-affine: same cic -> same XCD L2
  const int rest = blk >> 3;          // 0..223
  const int ip = rest / 14;           // image pair 0..15
  const int ohp = rest - ip * 14;     // 0..13
  const int b0 = ip * 2, b1 = ip * 2 + 1;

  const char* xb = (const char*)xt;
  const char* wb = (const char*)wt;

  // A lane bases (per image). Slab j = input row h = 4*ohp + j.
  const char* ab0 = xb + ((size_t)(b0 * 64 + 4 * ohp) * 32768 + cic * 4096 +
                          hh * 1024 + m * 16);
  const char* ab1 = ab0 + (size_t)64 * 32768;  // adjacent image
  // B lane base.
  const char* bb = wb + (cic * 2048 + hh * 512 + m * 16);

#define ALOAD(AB, J, S, KW)                                                    \
  (*(const f16x8*)((AB) + (J) * 32768 + (S) * 2048 + ((KW)&1) * 512 +          \
                   ((KW) >> 1) * 16))
#define BLOAD(KK, S) (*(const f16x8*)(bb + (size_t)(KK)*16384 + (S)*1024))

  f32x16 acc00, acc01, acc10, acc11;  // acc[t][im]
#pragma unroll
  for (int i = 0; i < 16; ++i) {
    acc00[i] = 0.f; acc01[i] = 0.f; acc10[i] = 0.f; acc11[i] = 0.f;
  }

  // step st = j*18 + s*9 + kw, st in [0,198). T0 (oh=2ohp, kh=j) active j<=8;
  // T1 (oh=2ohp+1, kh=j-2) active j>=2.
  f16x8 a0s[3], a1s[3], b0s[6], b1s[6];
#pragma unroll
  for (int st = 0; st < 3; ++st) {    // A prologue (steps 0..2, j=0)
    a0s[st] = ALOAD(ab0, 0, st / 9, st % 9);
    a1s[st] = ALOAD(ab1, 0, st / 9, st % 9);
  }
#pragma unroll
  for (int st = 0; st < 6; ++st)      // B prologue (steps 0..5: j=0, T0 only)
    b0s[st] = BLOAD(st % 9, st / 9);

#pragma unroll
  for (int st = 0; st < 198; ++st) {
    const int j = st / 18;
    const int r = st - j * 18;
    const bool t0 = (j <= 8), t1 = (j >= 2);
    const f16x8 A0 = a0s[st % 3];
    const f16x8 A1 = a1s[st % 3];
    f16x8 B0, B1;
    if (t0) B0 = b0s[st % 6];
    if (t1) B1 = b1s[st % 6];
    // prefetch A for st+3
    if (st + 3 < 198) {
      const int stn = st + 3;
      const int jn = stn / 18, rn = stn - jn * 18;
      a0s[stn % 3] = ALOAD(ab0, jn, rn / 9, rn % 9);
      a1s[stn % 3] = ALOAD(ab1, jn, rn / 9, rn % 9);
    }
    // prefetch B for st+6
    if (st + 6 < 198) {
      const int stn = st + 6;
      const int jn = stn / 18, rn = stn - jn * 18;
      const int sn = rn / 9, kwn = rn - sn * 9;
      if (jn <= 8) b0s[stn % 6] = BLOAD(jn * 9 + kwn, sn);
      if (jn >= 2) b1s[stn % 6] = BLOAD((jn - 2) * 9 + kwn, sn);
    }
    if (t0) { acc00 = MFMA(A0, B0, acc00); acc01 = MFMA(A1, B0, acc01); }
    if (t1) { acc10 = MFMA(A0, B1, acc10); acc11 = MFMA(A1, B1, acc11); }
  }
#undef ALOAD
#undef BLOAD

  // Store 4 tiles. C layout: col(co) = lane&31, row(ow) = (r&3)+8*(r>>2)+4*hh.
  float* cp = convp + (size_t)cic * 802816;
#pragma unroll
  for (int t = 0; t < 2; ++t) {
#pragma unroll
    for (int im = 0; im < 2; ++im) {
      const f32x16 a = t == 0 ? (im == 0 ? acc00 : acc01)
                              : (im == 0 ? acc10 : acc11);
      const int bimg = ip * 2 + im;
      const int pbase = bimg * 784 + (2 * ohp + t) * 28;
#pragma unroll
      for (int rI = 0; rI < 16; ++rI) {
        const int row = (rI & 3) + 8 * (rI >> 2) + 4 * hh;
        if (row < 28) cp[(size_t)(pbase + row) * 32 + m] = a[rI];
      }
    }
  }
}

// ---------------------------------------------------------------------------
// Kernel 4: epilogue. v = sum(8 cic partials)+bias; sq=8v^2;
// scale = sq/((1+sq)*sqrt(sq+1e-8)); y=v*scale broadcast to 8 t-slots.
// ---------------------------------------------------------------------------
__global__ __launch_bounds__(256) void epilogue(const float* __restrict__ convp,
                                                const float* __restrict__ bias,
                                                float* __restrict__ out) {
  const int gi = blockIdx.x * 256 + threadIdx.x;  // 100352 total, exact grid
  const int base = gi * 8;
  const int p = gi >> 2;
  const int co0 = (gi & 3) * 8;
  const int bi = p / 784;
  const int pix = p - bi * 784;
  f32x4 v0 = {0.f, 0.f, 0.f, 0.f}, v1 = {0.f, 0.f, 0.f, 0.f};
#pragma unroll
  for (int qq = 0; qq < 8; ++qq) {
    v0 += *(const f32x4*)&convp[(size_t)qq * 802816 + base];
    v1 += *(const f32x4*)&convp[(size_t)qq * 802816 + base + 4];
  }
  float vb[8];
#pragma unroll
  for (int jj = 0; jj < 4; ++jj) {
    vb[jj] = v0[jj] + bias[co0 + jj];
    vb[4 + jj] = v1[jj] + bias[co0 + 4 + jj];
  }
  float* ob = out + (size_t)bi * 200704 + pix * 8;
#pragma unroll
  for (int jj = 0; jj < 8; ++jj) {
    const float vv = vb[jj];
    const float sq = 8.f * vv * vv;
    const float scale = sq / ((1.f + sq) * sqrtf(sq + 1e-8f));
    const float y = vv * scale;
    const f32x4 qv = {y, y, y, y};
    float* o = ob + (size_t)(co0 + jj) * 6272;
    *(f32x4*)o = qv;
    *(f32x4*)(o + 4) = qv;
  }
}

// ---------------------------------------------------------------------------
extern "C" void kernel_launch(void* const* d_in, const int* in_sizes, int n_in,
                              void* d_out, int out_size, void* d_ws,
                              size_t ws_size, hipStream_t stream) {
  const float* x = (const float*)d_in[0];     // [32,256,64,64]
  const float* W = (const float*)d_in[1];     // [32,256,9,9]
  const float* bias = (const float*)d_in[2];  // [32]
  float* out = (float*)d_out;                 // 6422528 f32

  char* ws = (char*)d_ws;
  f16* xt = (f16*)ws;                                // 67,108,864 B
  f16* wt = (f16*)(ws + 67108864);                   //  1,327,104 B
  float* convp = (float*)(ws + 67108864 + 1327104);  // 25,690,112 B (8 parts)

  nchw_to_nhwc_f16<<<dim3(2048), dim3(256), 0, stream>>>(x, xt);
  pack_w<<<dim3(64), dim3(256), 0, stream>>>(W, wt);
  conv_direct<<<dim3(1792), dim3(64), 0, stream>>>(xt, wt, convp);
  epilogue<<<dim3(392), dim3(256), 0, stream>>>(convp, bias, out);
}